// Round 3
// baseline (161.671 us; speedup 1.0000x reference)
//
#include <hip/hip_runtime.h>
#include <math.h>
#include <type_traits>

// SoftMSM loss on MI355X — round 18.
// R17 base (cross-step pipelined windows, 110.5 us). Changes:
//  1. Fwd wave restructured bwd-style: WCELL split into WEXP (s1/arg/exp ->
//     persistent sA/eA banks, issued >=3 sched-regions before use) and
//     inline packaging (Bs/Cs/gates/cndmask) at the consuming recurrence
//     iteration. Kills the exp->consume 2-instr gap that the sched_barrier
//     region walls prevented the scheduler from fixing (trans latency
//     ~16-32 cyc x 16 exps/step on the critical fwd wave).
//  2. Reduction fused: hipMemsetAsync(out) + per-block atomicAdd; the
//     reduce_kernel launch is gone.
// Bwd wave, combine: R17 verbatim.
//
//   E_total = sum_j Gb[256,j] * ( Em(256,j)*E[255,j-1] + Wu(256,j)*E[255,j] )
// Bwd DP in reversed coords (x'_i = x[511-i], y'_j = y[511-j]):
//   Gb'[i',j'] = A'*Gb'[i'-1,j'-1] + B'*Gb'[i'-1,j'] + C'*Gb'[i',j'-1]
//   (window entry m of row r = exp(2-(X~_r - Y~_{j'base+m-1})^2); B uses m+1,
//    C of row r uses row r+1's window — all verified in R14.)

#define TT 512
#define BATCH 64
#define G 8
#define NPH 128                  // row-pairs per half; steps/wave = 191
#define C1F 1.2011224087864498f  // sqrt(log2 e)
#define C2F 2.8853900817779268f  // 2*log2 e
#define K2F 0.13533528323661270f // e^-2
#define LN2F 0.69314718055994531f
#define NEG_BIG (-1e30f)

#if __has_builtin(__builtin_amdgcn_exp2f)
#define EXP2F(x) __builtin_amdgcn_exp2f(x)
#else
#define EXP2F(x) __expf((x) * LN2F)
#endif

typedef float v2f __attribute__((ext_vector_type(2)));

__device__ __forceinline__ float dpp_shr1_f(float src, float old) {
  return __int_as_float(__builtin_amdgcn_update_dpp(
      __float_as_int(old), __float_as_int(src), 0x138, 0xF, 0xF, false));
}
__device__ __forceinline__ int dpp_shr1_i(int src, int old) {
  return __builtin_amdgcn_update_dpp(old, src, 0x138, 0xF, 0xF, false);
}

__global__ __launch_bounds__(128, 1) void msm_kernel(const float* __restrict__ x,
                                                     const float* __restrict__ y,
                                                     float* __restrict__ out) {
  const int b = blockIdx.x;
  const int tid = threadIdx.x;
  const int wv = tid >> 6;
  const int j = tid & 63;
  const float* xb = x + b * TT;
  const float* yb = y + b * TT;

  __shared__ float2 FXC[NPH], FDX[NPH], FEX[NPH];   // fwd rows 0..255
  __shared__ float2 BXA[NPH], BDX[NPH], BEX[NPH];   // bwd primed rows 0..255
  __shared__ float LF[TT], LG[TT], TERMS[TT];

  // ---- staging (R14 verbatim) ----
  if (wv == 0) {
    float4 xq = ((const float4*)xb)[j];
    float rx[4] = {xq.x, xq.y, xq.z, xq.w};
    float prev = (j > 0) ? xb[4 * j - 1] : 0.0f;
    float cc[4], dd[4], ee[4];
#pragma unroll
    for (int k = 0; k < 4; ++k) {
      float dx = rx[k] - prev;
      prev = rx[k];
      cc[k] = rx[k] * C1F;
      dd[k] = dx;
      ee[k] = __expf(-dx * dx);
    }
    FXC[2 * j] = make_float2(cc[0], cc[1]);
    FXC[2 * j + 1] = make_float2(cc[2], cc[3]);
    FDX[2 * j] = make_float2(dd[0], dd[1]);
    FDX[2 * j + 1] = make_float2(dd[2], dd[3]);
    FEX[2 * j] = make_float2(ee[0], ee[1]);
    FEX[2 * j + 1] = make_float2(ee[2], ee[3]);
  } else {
    float cc[4], dd[4], ee[4];
#pragma unroll
    for (int k = 0; k < 4; ++k) {
      int rp = 4 * j + k;
      int i1 = 512 - rp; if (i1 > 511) i1 = 511;
      int i2 = 511 - rp;
      float xa = xb[i1];
      float dxp = xb[i2] - xa;
      cc[k] = xa * C1F;
      dd[k] = dxp;
      ee[k] = __expf(-dxp * dxp);
    }
    BXA[2 * j] = make_float2(cc[0], cc[1]);
    BXA[2 * j + 1] = make_float2(cc[2], cc[3]);
    BDX[2 * j] = make_float2(dd[0], dd[1]);
    BDX[2 * j + 1] = make_float2(dd[2], dd[3]);
    BEX[2 * j] = make_float2(ee[0], ee[1]);
    BEX[2 * j + 1] = make_float2(ee[2], ee[3]);
  }
  __syncthreads();

  float EpF[G];
#pragma unroll
  for (int k = 0; k < G; ++k) EpF[k] = 0.0f;
  int kaccF = 0;

  if (wv == 0) {
    // ========== FORWARD (exp-only pipelined windows, inline packaging) ==========
    float yc[G], dyS[G], edy2[G];
    {
      const float4* yv = (const float4*)yb;
      float4 a0 = yv[j * 2], a1 = yv[j * 2 + 1];
      float ry[G] = {a0.x, a0.y, a0.z, a0.w, a1.x, a1.y, a1.z, a1.w};
      float prev = (j > 0) ? yb[8 * j - 1] : 0.0f;
#pragma unroll
      for (int k = 0; k < G; ++k) {
        float dy = ry[k] - prev;
        prev = ry[k];
        yc[k] = ry[k] * C1F;
        dyS[k] = dy;
        edy2[k] = __expf(-dy * dy);
      }
    }
    float dc0 = 0.0f, dc1 = 0.0f, dc2 = 0.0f;
    float2 rdEx = FXC[0], rdEd = FDX[0], rdEe = FEX[0];
    float2 rdOx, rdOd, rdOe;

    // persistent exp-window banks (live across steps): s1 and A per column
    v2f sA[G], eA[G];

#define WEXP(kk)                                                        \
    {                                                                   \
      v2f s1 = xcp - yc[kk];                                            \
      v2f arg = C2F - s1 * s1;                                          \
      sA[kk] = s1;                                                      \
      eA[kk].x = EXP2F(arg.x);                                          \
      eA[kk].y = EXP2F(arg.y);                                          \
    }

    // prologue: exp windows 0..2 for step 0 (from the preloaded E bank)
    {
      v2f xcp = {rdEx.x, rdEx.y};
      WEXP(0) WEXP(1) WEXP(2)
    }

    auto fstep = [&](int t, auto phc, float2& xcU, float2& dxU, float2& exU,
                     float2& xcL, float2& dxL, float2& exL) {
      constexpr int PH = decltype(phc)::value;
      {
        int pn = t + 2 - j;
        pn = (pn < 0) ? 0 : ((pn > NPH - 1) ? NPH - 1 : pn);
        xcL = FXC[pn]; dxL = FDX[pn]; exL = FEX[pn];
      }
      float r0 = dpp_shr1_f(dc0, 0.0f);
      float r1 = dpp_shr1_f(dc1, 0.0f);
      float r2 = dpp_shr1_f(dc2, 0.0f);
      int k_in = dpp_shr1_i(kaccF, kaccF);
      const int p = t - j;
      if (PH == 0) {
        if (t == 0 && j == 0) r0 = K2F;
      }
      bool act = true;
      int kacc_e = kaccF;
      if (PH == 0) { act = (p >= 0); kacc_e = (p == 0) ? k_in : kaccF; }
      else if (PH == 2) { act = (p < NPH); }
      const int knew = (k_in > kacc_e) ? k_in : kacc_e;
      const float mMe = ldexpf(1.0f, kacc_e - knew);
      const float mIn = ldexpf(1.0f, k_in - knew);
      const float dv0 = r0 * mIn, dv1 = r1 * mIn, dv2 = r2 * mIn;
      const float nd0 = dc2 * mMe;
      float u[G];
#pragma unroll
      for (int k = 0; k < G; ++k) u[k] = EpF[k] * mMe;

      v2f xcp = {xcU.x, xcU.y};
      const v2f dxp = {xcU.x, xcU.y};  // placeholder overwritten below
      const v2f dxv = {dxU.x, dxU.y};
      const v2f exv = {exU.x, exU.y};
      (void)dxp;
      // exp windows 0..2 were built at the previous step's tail
      float T0[G], T1[G];
#pragma unroll
      for (int k = 0; k < G; ++k) {
        if (k + 3 < G) WEXP(k + 3)
        __builtin_amdgcn_sched_barrier(0);
        // inline packaging for column k (exp issued >=3 regions earlier)
        v2f s1 = sA[k];
        v2f A = eA[k];
        v2f Bs = A * K2F + exv;
        v2f Cs = A * K2F + edy2[k];
        v2f gu = dxv * s1;
        v2f gl = dyS[k] * s1;
        float Bx = (gu.x > 0.0f) ? Bs.x : 1.0f;
        float By = (gu.y > 0.0f) ? Bs.y : 1.0f;
        float Cx = (gl.x < 0.0f) ? Cs.x : 1.0f;
        float Cy = (gl.y < 0.0f) ? Cs.y : 1.0f;
        float da = (k == 0) ? dv0 : u[k - 1];
        float pa = __fmaf_rn(da, A.x, u[k] * Bx);
        T0[k] = __fmaf_rn((k == 0) ? dv1 : T0[k - 1], Cx, pa);
        float db = (k == 0) ? dv1 : T0[k - 1];
        float pb = __fmaf_rn(db, A.y, T0[k] * By);
        T1[k] = __fmaf_rn((k == 0) ? dv2 : T1[k - 1], Cy, pb);
      }
      const float ndc1 = T0[G - 1];
      float m0 = fmaxf(fmaxf(T1[0], T1[1]), T1[2]);
      float m1 = fmaxf(fmaxf(T1[3], T1[4]), T1[5]);
      float m2 = fmaxf(fmaxf(T1[6], T1[7]), nd0);
      float vmax = fmaxf(fmaxf(m0, m1), fmaxf(m2, ndc1));
      unsigned ue = (__float_as_uint(vmax) >> 23) & 0xFFu;
      int e = (int)ue - 126;
      float sc = ldexpf(1.0f, -e);
      if (PH == 1) {
#pragma unroll
        for (int k = 0; k < G; ++k) EpF[k] = T1[k] * sc;
        dc0 = nd0 * sc; dc1 = ndc1 * sc; dc2 = EpF[G - 1];
        kaccF = knew + e;
      } else {
#pragma unroll
        for (int k = 0; k < G; ++k) EpF[k] = act ? T1[k] * sc : EpF[k];
        dc0 = act ? nd0 * sc : dc0;
        dc1 = act ? ndc1 * sc : dc1;
        dc2 = act ? EpF[G - 1] : dc2;
        kaccF = act ? knew + e : kaccF;
      }
      // tail: next step's exp windows 0..2 from the L bank just loaded.
      // Overlaps the serial renorm in the same scheduling region.
      xcp.x = xcL.x; xcp.y = xcL.y;
      WEXP(0) WEXP(1) WEXP(2)
    };
#undef WEXP
    std::integral_constant<int, 0> P0;
    std::integral_constant<int, 1> P1;
    std::integral_constant<int, 2> P2;
    for (int t = 0; t < 64; t += 2) {
      fstep(t, P0, rdEx, rdEd, rdEe, rdOx, rdOd, rdOe);
      fstep(t + 1, P0, rdOx, rdOd, rdOe, rdEx, rdEd, rdEe);
    }
    for (int t = 64; t < 128; t += 2) {
      fstep(t, P1, rdEx, rdEd, rdEe, rdOx, rdOd, rdOe);
      fstep(t + 1, P1, rdOx, rdOd, rdOe, rdEx, rdEd, rdEe);
    }
    for (int t = 128; t < 192; t += 2) {
      fstep(t, P2, rdEx, rdEd, rdEe, rdOx, rdOd, rdOe);
      fstep(t + 1, P2, rdOx, rdOd, rdOe, rdEx, rdEd, rdEe);
    }
#pragma unroll
    for (int k = 0; k < G; ++k) {
      float le = (EpF[k] > 0.0f) ? __logf(EpF[k]) : NEG_BIG;
      LF[8 * j + k] = le + (float)kaccF * LN2F - (float)(255 + 8 * j + k);
    }
  } else {
    // ============ BACKWARD (R17 verbatim: pipelined windows, deep prefetch) ============
    float ycP[G + 1], dyP[G], edy2P[G];
    {
#pragma unroll
      for (int k = 0; k <= G; ++k) {
        int idx = 512 - 8 * j - k; if (idx > 511) idx = 511;
        ycP[k] = yb[idx] * C1F;
      }
#pragma unroll
      for (int k = 0; k < G; ++k) {
        int ia = 511 - 8 * j - k;
        int ib = 512 - 8 * j - k; if (ib > 511) ib = 511;
        float d = yb[ia] - yb[ib];
        dyP[k] = d;
        edy2P[k] = __expf(-d * d);
      }
    }
    float dc0 = 0.0f, dc1 = 0.0f, dc2 = 0.0f;
    float sBk0[G + 1], eBk0[G + 1], sBk1[G + 1], eBk1[G + 1];
    float sV[G + 1], eV[G + 1];
    {
      float xa0 = BXA[0].x;
#pragma unroll
      for (int k = 0; k <= G; ++k) {
        float s = xa0 - ycP[k];
        sBk0[k] = s;
        eBk0[k] = EXP2F(C2F - s * s);
      }
    }
    float2 cxA = BXA[0], cdx = BDX[0], cex = BEX[0];
    float2 nxA, ndx, nex;
    {
      int pn = 1 - j;
      pn = (pn < 0) ? 0 : pn;
      nxA = BXA[pn]; ndx = BDX[pn]; nex = BEX[pn];
    }
    {
      float xb0 = cxA.y, xb1 = nxA.x;
#pragma unroll
      for (int mm = 0; mm < 5; ++mm) {
        float s0 = xb0 - ycP[mm]; sV[mm] = s0; eV[mm] = EXP2F(C2F - s0 * s0);
        float s1 = xb1 - ycP[mm]; sBk1[mm] = s1; eBk1[mm] = EXP2F(C2F - s1 * s1);
      }
    }

    auto bstep = [&](int t, auto phc, float (&sU)[G + 1], float (&eU)[G + 1],
                     float (&sO)[G + 1], float (&eO)[G + 1]) {
      constexpr int PH = decltype(phc)::value;
      const int p = t - j;
      int pn2 = t + 2 - j;
      pn2 = (pn2 < 0) ? 0 : ((pn2 > NPH - 1) ? NPH - 1 : pn2);
      float2 xA2 = BXA[pn2], dx2 = BDX[pn2], ex2 = BEX[pn2];
      float r0 = dpp_shr1_f(dc0, 0.0f);
      float r1 = dpp_shr1_f(dc1, 0.0f);
      float r2 = dpp_shr1_f(dc2, 0.0f);
      int k_in = dpp_shr1_i(kaccF, kaccF);
      const bool seed = (PH == 0) && (t == 0) && (j == 0);
      if (seed) r0 = 1.0f;                         // Gb'[0,0] = 1 (with A:=1)
      bool act = true;
      int kacc_e = kaccF;
      if (PH == 0) { act = (p >= 0); kacc_e = (p == 0) ? k_in : kaccF; }
      else if (PH == 2) { act = (p < NPH); }
      const int knew = (k_in > kacc_e) ? k_in : kacc_e;
      const float mMe = ldexpf(1.0f, kacc_e - knew);
      const float mIn = ldexpf(1.0f, k_in - knew);
      const float dv0 = r0 * mIn, dv1 = r1 * mIn, dv2 = r2 * mIn;
      const float nd0 = dc2 * mMe;
      float u[G];
#pragma unroll
      for (int k = 0; k < G; ++k) u[k] = EpF[k] * mMe;

      const v2f xbn = {cxA.y, nxA.x};
#define BWIN(mm)                                                        \
      {                                                                 \
        v2f sw = xbn - ycP[mm];                                         \
        v2f arg = C2F - sw * sw;                                        \
        sV[mm] = sw.x;  eV[mm] = EXP2F(arg.x);                          \
        sO[mm] = sw.y;  eO[mm] = EXP2F(arg.y);                          \
      }
      const float dxa = cdx.x, dxb = cdx.y, exa = cex.x, exb = cex.y;
      float T0[G], T1[G];
#pragma unroll
      for (int k = 0; k < G; ++k) {
        if (k + 5 <= G) BWIN(k + 5)
        __builtin_amdgcn_sched_barrier(0);
        float Aa = eU[k];
        if (seed && k == 0) Aa = 1.0f;
        float Ba = (dxa * sU[k + 1] < 0.0f) ? __fmaf_rn(eU[k + 1], K2F, exa) : 1.0f;
        float Ca = (dyP[k] * sV[k] > 0.0f) ? __fmaf_rn(eV[k], K2F, edy2P[k]) : 1.0f;
        float Ab = eV[k];
        float Bb = (dxb * sV[k + 1] < 0.0f) ? __fmaf_rn(eV[k + 1], K2F, exb) : 1.0f;
        float Cb = (dyP[k] * sO[k] > 0.0f) ? __fmaf_rn(eO[k], K2F, edy2P[k]) : 1.0f;
        float da = (k == 0) ? dv0 : u[k - 1];
        float pa = __fmaf_rn(da, Aa, u[k] * Ba);
        T0[k] = __fmaf_rn((k == 0) ? dv1 : T0[k - 1], Ca, pa);
        float db = (k == 0) ? dv1 : T0[k - 1];
        float pb = __fmaf_rn(db, Ab, T0[k] * Bb);
        T1[k] = __fmaf_rn((k == 0) ? dv2 : T1[k - 1], Cb, pb);
      }
#undef BWIN
      const float ndc1 = T0[G - 1];
      float m0 = fmaxf(fmaxf(T1[0], T1[1]), T1[2]);
      float m1 = fmaxf(fmaxf(T1[3], T1[4]), T1[5]);
      float m2 = fmaxf(fmaxf(T1[6], T1[7]), nd0);
      float vmax = fmaxf(fmaxf(m0, m1), fmaxf(m2, ndc1));
      unsigned ue = (__float_as_uint(vmax) >> 23) & 0xFFu;
      int e = (int)ue - 126;
      float sc = ldexpf(1.0f, -e);
      if (PH == 1) {
#pragma unroll
        for (int k = 0; k < G; ++k) EpF[k] = T1[k] * sc;
        dc0 = nd0 * sc; dc1 = ndc1 * sc; dc2 = EpF[G - 1];
        kaccF = knew + e;
      } else {
#pragma unroll
        for (int k = 0; k < G; ++k) EpF[k] = act ? T1[k] * sc : EpF[k];
        dc0 = act ? nd0 * sc : dc0;
        dc1 = act ? ndc1 * sc : dc1;
        dc2 = act ? EpF[G - 1] : dc2;
        kaccF = act ? knew + e : kaccF;
      }
      // tail: next step's BWIN(0..4) — V_{t+1}[0..4] and (via sU/eU, the
      // out-bank of step t+1) U_{t+2}[0..4]. {nxA.y, xA2.x} equals the old
      // step-(t+1) {cxA.y, nxA.x}. Overlaps the serial renorm above.
      {
        float xb0 = nxA.y, xb1 = xA2.x;
#pragma unroll
        for (int mm = 0; mm < 5; ++mm) {
          float s0 = xb0 - ycP[mm]; sV[mm] = s0; eV[mm] = EXP2F(C2F - s0 * s0);
          float s1 = xb1 - ycP[mm]; sU[mm] = s1; eU[mm] = EXP2F(C2F - s1 * s1);
        }
      }
      cxA = nxA; cdx = ndx; cex = nex;    // rotate (depth-2 prefetch)
      nxA = xA2; ndx = dx2; nex = ex2;
    };
    std::integral_constant<int, 0> P0;
    std::integral_constant<int, 1> P1;
    std::integral_constant<int, 2> P2;
    for (int t = 0; t < 64; t += 2) {
      bstep(t, P0, sBk0, eBk0, sBk1, eBk1);
      bstep(t + 1, P0, sBk1, eBk1, sBk0, eBk0);
    }
    for (int t = 64; t < 128; t += 2) {
      bstep(t, P1, sBk0, eBk0, sBk1, eBk1);
      bstep(t + 1, P1, sBk1, eBk1, sBk0, eBk0);
    }
    for (int t = 128; t < 192; t += 2) {       // t=191 inert (all p >= NPH)
      bstep(t, P2, sBk0, eBk0, sBk1, eBk1);
      bstep(t + 1, P2, sBk1, eBk1, sBk0, eBk0);
    }
#pragma unroll
    for (int k = 0; k < G; ++k) {
      float le = (EpF[k] > 0.0f) ? __logf(EpF[k]) : NEG_BIG;
      LG[511 - (8 * j + k)] = le + (float)kaccF * LN2F - (float)(255 + 8 * j + k);
    }
  }
  __syncthreads();

  // ---- combine (R14 verbatim) ----
  {
    const float sx = xb[256];
    const float dxs = sx - xb[255];
    const float ex2s = __expf(-dxs * dxs);
#pragma unroll
    for (int c = 0; c < 4; ++c) {
      int jj = 4 * tid + c;
      float d = sx - yb[jj];
      float m2 = d * d;
      float lw = (dxs * d > 0.0f) ? __logf(ex2s + __expf(-m2)) : 0.0f;
      float t1 = ((jj > 0) ? LF[jj - 1] : NEG_BIG) - m2;
      float t2 = LF[jj] - 1.0f + lw;
      float mt = fmaxf(t1, t2);
      float term = NEG_BIG;
      if (mt > -1e29f)
        term = LG[jj] + mt + __logf(__expf(t1 - mt) + __expf(t2 - mt));
      TERMS[jj] = term;
    }
  }
  __syncthreads();
  if (wv == 0) {
    float v[8];
    float M = NEG_BIG;
#pragma unroll
    for (int i = 0; i < 8; ++i) {
      v[i] = TERMS[8 * j + i];
      M = fmaxf(M, v[i]);
    }
#pragma unroll
    for (int off = 1; off < 64; off <<= 1) M = fmaxf(M, __shfl_xor(M, off));
    float S = 0.0f;
#pragma unroll
    for (int i = 0; i < 8; ++i) S += __expf(v[i] - M);
#pragma unroll
    for (int off = 1; off < 64; off <<= 1) S += __shfl_xor(S, off);
    if (j == 0) atomicAdd(out, -(M + __logf(S)) * (1.0f / BATCH));
  }
}

extern "C" void kernel_launch(void* const* d_in, const int* in_sizes, int n_in,
                              void* d_out, int out_size, void* d_ws, size_t ws_size,
                              hipStream_t stream) {
  const float* x = (const float*)d_in[0];
  const float* y = (const float*)d_in[1];
  float* out = (float*)d_out;
  (void)d_ws; (void)ws_size;
  hipMemsetAsync(d_out, 0, out_size, stream);
  msm_kernel<<<BATCH, 128, 0, stream>>>(x, y, out);
}

// Round 6
// 159.335 us; speedup vs baseline: 1.0147x; 1.0147x over previous
//
#include <hip/hip_runtime.h>
#include <math.h>
#include <type_traits>

// SoftMSM loss on MI355X — round 20 (resubmit; previous attempt hit an
// infra failure "container failed twice" — kernel never ran).
// R18 base (110.2 us, verified). Change: DEFERRED RENORM, PER-LANE SCALE.
//   R19's wave-uniform scale failed for range reasons (512-column wavefront
//   spans >> 87 nats; LF/LG finite-support bands can be disjoint at the
//   seam). Per-lane kacc and the per-step dpp alignment (k_in, mIn/mMe)
//   are load-bearing and stay. The renorm block (11-fmax tree -> exponent
//   extract -> sc -> 12 rescale muls -> kacc+=e) is pure range maintenance:
//   it now runs every 4th step only (RN template param). Invariant
//   true = stored*2^kacc holds exactly on skipped steps (kacc = knew);
//   growth between renorms <= ~2^84 worst case < 2^127. Final LF/LG are
//   exact at any un-renormalized state. All lanes renorm at the same steps
//   so neighbor kacc gaps stay small.
// Fwd/bwd window pipelining (R17/R18), combine, atomicAdd reduce: unchanged.
//
//   E_total = sum_j Gb[256,j] * ( Em(256,j)*E[255,j-1] + Wu(256,j)*E[255,j] )
// Bwd DP in reversed coords (x'_i = x[511-i], y'_j = y[511-j]):
//   Gb'[i',j'] = A'*Gb'[i'-1,j'-1] + B'*Gb'[i'-1,j'] + C'*Gb'[i',j'-1]
//   (window entry m of row r = exp(2-(X~_r - Y~_{j'base+m-1})^2); B uses m+1,
//    C of row r uses row r+1's window — all verified in R14.)

#define TT 512
#define BATCH 64
#define G 8
#define NPH 128                  // row-pairs per half; steps/wave = 191
#define C1F 1.2011224087864498f  // sqrt(log2 e)
#define C2F 2.8853900817779268f  // 2*log2 e
#define K2F 0.13533528323661270f // e^-2
#define LN2F 0.69314718055994531f
#define NEG_BIG (-1e30f)

#if __has_builtin(__builtin_amdgcn_exp2f)
#define EXP2F(x) __builtin_amdgcn_exp2f(x)
#else
#define EXP2F(x) __expf((x) * LN2F)
#endif

typedef float v2f __attribute__((ext_vector_type(2)));

__device__ __forceinline__ float dpp_shr1_f(float src, float old) {
  return __int_as_float(__builtin_amdgcn_update_dpp(
      __float_as_int(old), __float_as_int(src), 0x138, 0xF, 0xF, false));
}
__device__ __forceinline__ int dpp_shr1_i(int src, int old) {
  return __builtin_amdgcn_update_dpp(old, src, 0x138, 0xF, 0xF, false);
}

__global__ __launch_bounds__(128, 1) void msm_kernel(const float* __restrict__ x,
                                                     const float* __restrict__ y,
                                                     float* __restrict__ out) {
  const int b = blockIdx.x;
  const int tid = threadIdx.x;
  const int wv = tid >> 6;
  const int j = tid & 63;
  const float* xb = x + b * TT;
  const float* yb = y + b * TT;

  __shared__ float2 FXC[NPH], FDX[NPH], FEX[NPH];   // fwd rows 0..255
  __shared__ float2 BXA[NPH], BDX[NPH], BEX[NPH];   // bwd primed rows 0..255
  __shared__ float LF[TT], LG[TT], TERMS[TT];

  // ---- staging (R14 verbatim) ----
  if (wv == 0) {
    float4 xq = ((const float4*)xb)[j];
    float rx[4] = {xq.x, xq.y, xq.z, xq.w};
    float prev = (j > 0) ? xb[4 * j - 1] : 0.0f;
    float cc[4], dd[4], ee[4];
#pragma unroll
    for (int k = 0; k < 4; ++k) {
      float dx = rx[k] - prev;
      prev = rx[k];
      cc[k] = rx[k] * C1F;
      dd[k] = dx;
      ee[k] = __expf(-dx * dx);
    }
    FXC[2 * j] = make_float2(cc[0], cc[1]);
    FXC[2 * j + 1] = make_float2(cc[2], cc[3]);
    FDX[2 * j] = make_float2(dd[0], dd[1]);
    FDX[2 * j + 1] = make_float2(dd[2], dd[3]);
    FEX[2 * j] = make_float2(ee[0], ee[1]);
    FEX[2 * j + 1] = make_float2(ee[2], ee[3]);
  } else {
    float cc[4], dd[4], ee[4];
#pragma unroll
    for (int k = 0; k < 4; ++k) {
      int rp = 4 * j + k;
      int i1 = 512 - rp; if (i1 > 511) i1 = 511;
      int i2 = 511 - rp;
      float xa = xb[i1];
      float dxp = xb[i2] - xa;
      cc[k] = xa * C1F;
      dd[k] = dxp;
      ee[k] = __expf(-dxp * dxp);
    }
    BXA[2 * j] = make_float2(cc[0], cc[1]);
    BXA[2 * j + 1] = make_float2(cc[2], cc[3]);
    BDX[2 * j] = make_float2(dd[0], dd[1]);
    BDX[2 * j + 1] = make_float2(dd[2], dd[3]);
    BEX[2 * j] = make_float2(ee[0], ee[1]);
    BEX[2 * j + 1] = make_float2(ee[2], ee[3]);
  }
  __syncthreads();

  float EpF[G];
#pragma unroll
  for (int k = 0; k < G; ++k) EpF[k] = 0.0f;
  int kaccF = 0;

  if (wv == 0) {
    // ========== FORWARD (pipelined exp windows, deferred per-lane renorm) ==========
    float yc[G], dyS[G], edy2[G];
    {
      const float4* yv = (const float4*)yb;
      float4 a0 = yv[j * 2], a1 = yv[j * 2 + 1];
      float ry[G] = {a0.x, a0.y, a0.z, a0.w, a1.x, a1.y, a1.z, a1.w};
      float prev = (j > 0) ? yb[8 * j - 1] : 0.0f;
#pragma unroll
      for (int k = 0; k < G; ++k) {
        float dy = ry[k] - prev;
        prev = ry[k];
        yc[k] = ry[k] * C1F;
        dyS[k] = dy;
        edy2[k] = __expf(-dy * dy);
      }
    }
    float dc0 = 0.0f, dc1 = 0.0f, dc2 = 0.0f;
    float2 rdEx = FXC[0], rdEd = FDX[0], rdEe = FEX[0];
    float2 rdOx, rdOd, rdOe;

    // persistent exp-window banks (live across steps): s1 and A per column
    v2f sA[G], eA[G];

#define WEXP(kk)                                                        \
    {                                                                   \
      v2f s1 = xcp - yc[kk];                                            \
      v2f arg = C2F - s1 * s1;                                          \
      sA[kk] = s1;                                                      \
      eA[kk].x = EXP2F(arg.x);                                          \
      eA[kk].y = EXP2F(arg.y);                                          \
    }

    // prologue: exp windows 0..2 for step 0 (from the preloaded E bank)
    {
      v2f xcp = {rdEx.x, rdEx.y};
      WEXP(0) WEXP(1) WEXP(2)
    }

    auto fstep = [&](int t, auto phc, auto rnc, float2& xcU, float2& dxU,
                     float2& exU, float2& xcL, float2& dxL, float2& exL) {
      constexpr int PH = decltype(phc)::value;
      constexpr bool RN = decltype(rnc)::value;
      {
        int pn = t + 2 - j;
        pn = (pn < 0) ? 0 : ((pn > NPH - 1) ? NPH - 1 : pn);
        xcL = FXC[pn]; dxL = FDX[pn]; exL = FEX[pn];
      }
      float r0 = dpp_shr1_f(dc0, 0.0f);
      float r1 = dpp_shr1_f(dc1, 0.0f);
      float r2 = dpp_shr1_f(dc2, 0.0f);
      int k_in = dpp_shr1_i(kaccF, kaccF);
      const int p = t - j;
      if (PH == 0) {
        if (t == 0 && j == 0) r0 = K2F;
      }
      bool act = true;
      int kacc_e = kaccF;
      if (PH == 0) { act = (p >= 0); kacc_e = (p == 0) ? k_in : kaccF; }
      else if (PH == 2) { act = (p < NPH); }
      const int knew = (k_in > kacc_e) ? k_in : kacc_e;
      const float mMe = ldexpf(1.0f, kacc_e - knew);
      const float mIn = ldexpf(1.0f, k_in - knew);
      const float dv0 = r0 * mIn, dv1 = r1 * mIn, dv2 = r2 * mIn;
      const float nd0 = dc2 * mMe;
      float u[G];
#pragma unroll
      for (int k = 0; k < G; ++k) u[k] = EpF[k] * mMe;

      v2f xcp = {xcU.x, xcU.y};
      const v2f dxv = {dxU.x, dxU.y};
      const v2f exv = {exU.x, exU.y};
      // exp windows 0..2 were built at the previous step's tail
      float T0[G], T1[G];
#pragma unroll
      for (int k = 0; k < G; ++k) {
        if (k + 3 < G) WEXP(k + 3)
        __builtin_amdgcn_sched_barrier(0);
        // inline packaging for column k (exp issued >=3 regions earlier)
        v2f s1 = sA[k];
        v2f A = eA[k];
        v2f Bs = A * K2F + exv;
        v2f Cs = A * K2F + edy2[k];
        v2f gu = dxv * s1;
        v2f gl = dyS[k] * s1;
        float Bx = (gu.x > 0.0f) ? Bs.x : 1.0f;
        float By = (gu.y > 0.0f) ? Bs.y : 1.0f;
        float Cx = (gl.x < 0.0f) ? Cs.x : 1.0f;
        float Cy = (gl.y < 0.0f) ? Cs.y : 1.0f;
        float da = (k == 0) ? dv0 : u[k - 1];
        float pa = __fmaf_rn(da, A.x, u[k] * Bx);
        T0[k] = __fmaf_rn((k == 0) ? dv1 : T0[k - 1], Cx, pa);
        float db = (k == 0) ? dv1 : T0[k - 1];
        float pb = __fmaf_rn(db, A.y, T0[k] * By);
        T1[k] = __fmaf_rn((k == 0) ? dv2 : T1[k - 1], Cy, pb);
      }
      const float ndc1 = T0[G - 1];
      if constexpr (RN) {
        float m0 = fmaxf(fmaxf(T1[0], T1[1]), T1[2]);
        float m1 = fmaxf(fmaxf(T1[3], T1[4]), T1[5]);
        float m2 = fmaxf(fmaxf(T1[6], T1[7]), nd0);
        float vmax = fmaxf(fmaxf(m0, m1), fmaxf(m2, ndc1));
        unsigned ue = (__float_as_uint(vmax) >> 23) & 0xFFu;
        int e = (int)ue - 126;
        float sc = ldexpf(1.0f, -e);
        if (PH == 1) {
#pragma unroll
          for (int k = 0; k < G; ++k) EpF[k] = T1[k] * sc;
          dc0 = nd0 * sc; dc1 = ndc1 * sc; dc2 = EpF[G - 1];
          kaccF = knew + e;
        } else {
#pragma unroll
          for (int k = 0; k < G; ++k) EpF[k] = act ? T1[k] * sc : EpF[k];
          dc0 = act ? nd0 * sc : dc0;
          dc1 = act ? ndc1 * sc : dc1;
          dc2 = act ? EpF[G - 1] : dc2;
          kaccF = act ? knew + e : kaccF;
        }
      } else {
        if (PH == 1) {
#pragma unroll
          for (int k = 0; k < G; ++k) EpF[k] = T1[k];
          dc0 = nd0; dc1 = ndc1; dc2 = EpF[G - 1];
          kaccF = knew;
        } else {
#pragma unroll
          for (int k = 0; k < G; ++k) EpF[k] = act ? T1[k] : EpF[k];
          dc0 = act ? nd0 : dc0;
          dc1 = act ? ndc1 : dc1;
          dc2 = act ? EpF[G - 1] : dc2;
          kaccF = act ? knew : kaccF;
        }
      }
      // tail: build next step's exp windows 0..2 from the L bank just loaded.
      // Overlaps the serial renorm/boundary chain in the same region.
      xcp.x = xcL.x; xcp.y = xcL.y;
      WEXP(0) WEXP(1) WEXP(2)
    };
#undef WEXP
    std::integral_constant<int, 0> P0;
    std::integral_constant<int, 1> P1;
    std::integral_constant<int, 2> P2;
    std::integral_constant<bool, false> RF;
    std::integral_constant<bool, true> RT;
    for (int t = 0; t < 64; t += 4) {
      fstep(t,     P0, RF, rdEx, rdEd, rdEe, rdOx, rdOd, rdOe);
      fstep(t + 1, P0, RF, rdOx, rdOd, rdOe, rdEx, rdEd, rdEe);
      fstep(t + 2, P0, RF, rdEx, rdEd, rdEe, rdOx, rdOd, rdOe);
      fstep(t + 3, P0, RT, rdOx, rdOd, rdOe, rdEx, rdEd, rdEe);
    }
    for (int t = 64; t < 128; t += 4) {
      fstep(t,     P1, RF, rdEx, rdEd, rdEe, rdOx, rdOd, rdOe);
      fstep(t + 1, P1, RF, rdOx, rdOd, rdOe, rdEx, rdEd, rdEe);
      fstep(t + 2, P1, RF, rdEx, rdEd, rdEe, rdOx, rdOd, rdOe);
      fstep(t + 3, P1, RT, rdOx, rdOd, rdOe, rdEx, rdEd, rdEe);
    }
    for (int t = 128; t < 192; t += 4) {
      fstep(t,     P2, RF, rdEx, rdEd, rdEe, rdOx, rdOd, rdOe);
      fstep(t + 1, P2, RF, rdOx, rdOd, rdOe, rdEx, rdEd, rdEe);
      fstep(t + 2, P2, RF, rdEx, rdEd, rdEe, rdOx, rdOd, rdOe);
      fstep(t + 3, P2, RT, rdOx, rdOd, rdOe, rdEx, rdEd, rdEe);
    }
#pragma unroll
    for (int k = 0; k < G; ++k) {
      float le = (EpF[k] > 0.0f) ? __logf(EpF[k]) : NEG_BIG;
      LF[8 * j + k] = le + (float)kaccF * LN2F - (float)(255 + 8 * j + k);
    }
  } else {
    // ============ BACKWARD (pipelined windows, deferred per-lane renorm) ============
    float ycP[G + 1], dyP[G], edy2P[G];
    {
#pragma unroll
      for (int k = 0; k <= G; ++k) {
        int idx = 512 - 8 * j - k; if (idx > 511) idx = 511;
        ycP[k] = yb[idx] * C1F;
      }
#pragma unroll
      for (int k = 0; k < G; ++k) {
        int ia = 511 - 8 * j - k;
        int ib = 512 - 8 * j - k; if (ib > 511) ib = 511;
        float d = yb[ia] - yb[ib];
        dyP[k] = d;
        edy2P[k] = __expf(-d * d);
      }
    }
    float dc0 = 0.0f, dc1 = 0.0f, dc2 = 0.0f;
    float sBk0[G + 1], eBk0[G + 1], sBk1[G + 1], eBk1[G + 1];
    float sV[G + 1], eV[G + 1];
    {
      float xa0 = BXA[0].x;
#pragma unroll
      for (int k = 0; k <= G; ++k) {
        float s = xa0 - ycP[k];
        sBk0[k] = s;
        eBk0[k] = EXP2F(C2F - s * s);
      }
    }
    float2 cxA = BXA[0], cdx = BDX[0], cex = BEX[0];
    float2 nxA, ndx, nex;
    {
      int pn = 1 - j;
      pn = (pn < 0) ? 0 : pn;
      nxA = BXA[pn]; ndx = BDX[pn]; nex = BEX[pn];
    }
    {
      float xb0 = cxA.y, xb1 = nxA.x;
#pragma unroll
      for (int mm = 0; mm < 5; ++mm) {
        float s0 = xb0 - ycP[mm]; sV[mm] = s0; eV[mm] = EXP2F(C2F - s0 * s0);
        float s1 = xb1 - ycP[mm]; sBk1[mm] = s1; eBk1[mm] = EXP2F(C2F - s1 * s1);
      }
    }

    auto bstep = [&](int t, auto phc, auto rnc, float (&sU)[G + 1],
                     float (&eU)[G + 1], float (&sO)[G + 1], float (&eO)[G + 1]) {
      constexpr int PH = decltype(phc)::value;
      constexpr bool RN = decltype(rnc)::value;
      const int p = t - j;
      int pn2 = t + 2 - j;
      pn2 = (pn2 < 0) ? 0 : ((pn2 > NPH - 1) ? NPH - 1 : pn2);
      float2 xA2 = BXA[pn2], dx2 = BDX[pn2], ex2 = BEX[pn2];
      float r0 = dpp_shr1_f(dc0, 0.0f);
      float r1 = dpp_shr1_f(dc1, 0.0f);
      float r2 = dpp_shr1_f(dc2, 0.0f);
      int k_in = dpp_shr1_i(kaccF, kaccF);
      const bool seed = (PH == 0) && (t == 0) && (j == 0);
      if (seed) r0 = 1.0f;                         // Gb'[0,0] = 1 (with A:=1)
      bool act = true;
      int kacc_e = kaccF;
      if (PH == 0) { act = (p >= 0); kacc_e = (p == 0) ? k_in : kaccF; }
      else if (PH == 2) { act = (p < NPH); }
      const int knew = (k_in > kacc_e) ? k_in : kacc_e;
      const float mMe = ldexpf(1.0f, kacc_e - knew);
      const float mIn = ldexpf(1.0f, k_in - knew);
      const float dv0 = r0 * mIn, dv1 = r1 * mIn, dv2 = r2 * mIn;
      const float nd0 = dc2 * mMe;
      float u[G];
#pragma unroll
      for (int k = 0; k < G; ++k) u[k] = EpF[k] * mMe;

      // window entries 0..4 (V and O) were built at the previous step's tail
      const v2f xbn = {cxA.y, nxA.x};
#define BWIN(mm)                                                        \
      {                                                                 \
        v2f sw = xbn - ycP[mm];                                         \
        v2f arg = C2F - sw * sw;                                        \
        sV[mm] = sw.x;  eV[mm] = EXP2F(arg.x);                          \
        sO[mm] = sw.y;  eO[mm] = EXP2F(arg.y);                          \
      }
      const float dxa = cdx.x, dxb = cdx.y, exa = cex.x, exb = cex.y;
      float T0[G], T1[G];
#pragma unroll
      for (int k = 0; k < G; ++k) {
        if (k + 5 <= G) BWIN(k + 5)
        __builtin_amdgcn_sched_barrier(0);
        float Aa = eU[k];
        if (seed && k == 0) Aa = 1.0f;
        float Ba = (dxa * sU[k + 1] < 0.0f) ? __fmaf_rn(eU[k + 1], K2F, exa) : 1.0f;
        float Ca = (dyP[k] * sV[k] > 0.0f) ? __fmaf_rn(eV[k], K2F, edy2P[k]) : 1.0f;
        float Ab = eV[k];
        float Bb = (dxb * sV[k + 1] < 0.0f) ? __fmaf_rn(eV[k + 1], K2F, exb) : 1.0f;
        float Cb = (dyP[k] * sO[k] > 0.0f) ? __fmaf_rn(eO[k], K2F, edy2P[k]) : 1.0f;
        float da = (k == 0) ? dv0 : u[k - 1];
        float pa = __fmaf_rn(da, Aa, u[k] * Ba);
        T0[k] = __fmaf_rn((k == 0) ? dv1 : T0[k - 1], Ca, pa);
        float db = (k == 0) ? dv1 : T0[k - 1];
        float pb = __fmaf_rn(db, Ab, T0[k] * Bb);
        T1[k] = __fmaf_rn((k == 0) ? dv2 : T1[k - 1], Cb, pb);
      }
#undef BWIN
      const float ndc1 = T0[G - 1];
      if constexpr (RN) {
        float m0 = fmaxf(fmaxf(T1[0], T1[1]), T1[2]);
        float m1 = fmaxf(fmaxf(T1[3], T1[4]), T1[5]);
        float m2 = fmaxf(fmaxf(T1[6], T1[7]), nd0);
        float vmax = fmaxf(fmaxf(m0, m1), fmaxf(m2, ndc1));
        unsigned ue = (__float_as_uint(vmax) >> 23) & 0xFFu;
        int e = (int)ue - 126;
        float sc = ldexpf(1.0f, -e);
        if (PH == 1) {
#pragma unroll
          for (int k = 0; k < G; ++k) EpF[k] = T1[k] * sc;
          dc0 = nd0 * sc; dc1 = ndc1 * sc; dc2 = EpF[G - 1];
          kaccF = knew + e;
        } else {
#pragma unroll
          for (int k = 0; k < G; ++k) EpF[k] = act ? T1[k] * sc : EpF[k];
          dc0 = act ? nd0 * sc : dc0;
          dc1 = act ? ndc1 * sc : dc1;
          dc2 = act ? EpF[G - 1] : dc2;
          kaccF = act ? knew + e : kaccF;
        }
      } else {
        if (PH == 1) {
#pragma unroll
          for (int k = 0; k < G; ++k) EpF[k] = T1[k];
          dc0 = nd0; dc1 = ndc1; dc2 = EpF[G - 1];
          kaccF = knew;
        } else {
#pragma unroll
          for (int k = 0; k < G; ++k) EpF[k] = act ? T1[k] : EpF[k];
          dc0 = act ? nd0 : dc0;
          dc1 = act ? ndc1 : dc1;
          dc2 = act ? EpF[G - 1] : dc2;
          kaccF = act ? knew : kaccF;
        }
      }
      // tail: next step's BWIN(0..4) — V_{t+1}[0..4] and U_{t+2}[0..4].
      // {nxA.y, xA2.x} equals the old step-(t+1) {cxA.y, nxA.x}.
      {
        float xb0 = nxA.y, xb1 = xA2.x;
#pragma unroll
        for (int mm = 0; mm < 5; ++mm) {
          float s0 = xb0 - ycP[mm]; sV[mm] = s0; eV[mm] = EXP2F(C2F - s0 * s0);
          float s1 = xb1 - ycP[mm]; sU[mm] = s1; eU[mm] = EXP2F(C2F - s1 * s1);
        }
      }
      cxA = nxA; cdx = ndx; cex = nex;    // rotate (depth-2 prefetch)
      nxA = xA2; ndx = dx2; nex = ex2;
    };
    std::integral_constant<int, 0> P0;
    std::integral_constant<int, 1> P1;
    std::integral_constant<int, 2> P2;
    std::integral_constant<bool, false> RF;
    std::integral_constant<bool, true> RT;
    for (int t = 0; t < 64; t += 4) {
      bstep(t,     P0, RF, sBk0, eBk0, sBk1, eBk1);
      bstep(t + 1, P0, RF, sBk1, eBk1, sBk0, eBk0);
      bstep(t + 2, P0, RF, sBk0, eBk0, sBk1, eBk1);
      bstep(t + 3, P0, RT, sBk1, eBk1, sBk0, eBk0);
    }
    for (int t = 64; t < 128; t += 4) {
      bstep(t,     P1, RF, sBk0, eBk0, sBk1, eBk1);
      bstep(t + 1, P1, RF, sBk1, eBk1, sBk0, eBk0);
      bstep(t + 2, P1, RF, sBk0, eBk0, sBk1, eBk1);
      bstep(t + 3, P1, RT, sBk1, eBk1, sBk0, eBk0);
    }
    for (int t = 128; t < 192; t += 4) {       // t=191 inert (all p >= NPH)
      bstep(t,     P2, RF, sBk0, eBk0, sBk1, eBk1);
      bstep(t + 1, P2, RF, sBk1, eBk1, sBk0, eBk0);
      bstep(t + 2, P2, RF, sBk0, eBk0, sBk1, eBk1);
      bstep(t + 3, P2, RT, sBk1, eBk1, sBk0, eBk0);
    }
#pragma unroll
    for (int k = 0; k < G; ++k) {
      float le = (EpF[k] > 0.0f) ? __logf(EpF[k]) : NEG_BIG;
      LG[511 - (8 * j + k)] = le + (float)kaccF * LN2F - (float)(255 + 8 * j + k);
    }
  }
  __syncthreads();

  // ---- combine (R14 verbatim) ----
  {
    const float sx = xb[256];
    const float dxs = sx - xb[255];
    const float ex2s = __expf(-dxs * dxs);
#pragma unroll
    for (int c = 0; c < 4; ++c) {
      int jj = 4 * tid + c;
      float d = sx - yb[jj];
      float m2 = d * d;
      float lw = (dxs * d > 0.0f) ? __logf(ex2s + __expf(-m2)) : 0.0f;
      float t1 = ((jj > 0) ? LF[jj - 1] : NEG_BIG) - m2;
      float t2 = LF[jj] - 1.0f + lw;
      float mt = fmaxf(t1, t2);
      float term = NEG_BIG;
      if (mt > -1e29f)
        term = LG[jj] + mt + __logf(__expf(t1 - mt) + __expf(t2 - mt));
      TERMS[jj] = term;
    }
  }
  __syncthreads();
  if (wv == 0) {
    float v[8];
    float M = NEG_BIG;
#pragma unroll
    for (int i = 0; i < 8; ++i) {
      v[i] = TERMS[8 * j + i];
      M = fmaxf(M, v[i]);
    }
#pragma unroll
    for (int off = 1; off < 64; off <<= 1) M = fmaxf(M, __shfl_xor(M, off));
    float S = 0.0f;
#pragma unroll
    for (int i = 0; i < 8; ++i) S += __expf(v[i] - M);
#pragma unroll
    for (int off = 1; off < 64; off <<= 1) S += __shfl_xor(S, off);
    if (j == 0) atomicAdd(out, -(M + __logf(S)) * (1.0f / BATCH));
  }
}

extern "C" void kernel_launch(void* const* d_in, const int* in_sizes, int n_in,
                              void* d_out, int out_size, void* d_ws, size_t ws_size,
                              hipStream_t stream) {
  const float* x = (const float*)d_in[0];
  const float* y = (const float*)d_in[1];
  float* out = (float*)d_out;
  (void)d_ws; (void)ws_size;
  hipMemsetAsync(d_out, 0, out_size, stream);
  msm_kernel<<<BATCH, 128, 0, stream>>>(x, y, out);
}